// Round 8
// baseline (268.331 us; speedup 1.0000x reference)
//
#include <hip/hip_runtime.h>
#include <math.h>

#define DIM    2048
#define NEXP   64
#define BM     128
#define BK     32
#define TPB    128
#define XCOLS  128
#define WCOLS  64

typedef float f32x2 __attribute__((ext_vector_type(2)));
typedef float f32x4 __attribute__((ext_vector_type(4)));

// XOR swizzle (units of 4 floats). Writes: 64 lanes -> 64 distinct cols = 2/bank
// (free). Reads: broadcast groups, stride-8 cols -> 2-way (free). Mult-of-4 =>
// 16B alignment preserved; (a^sw)+i == (a+i)^sw for i<4 since sw has no bits<2.
#define SW(k) ((((k) >> 1) & 7) << 2)

// ---------------- Kernel 1: partial logits GEMM (packed fp32 FMA) ------------
// 128 tokens x 64 experts per block, 128 threads, per-thread 8 tok x 8 exp.
// Double-buffered LDS, ONE barrier per chunk, global loads issued before the
// compute phase so the implicit vmcnt(0) drain at the barrier is free.
__global__ __launch_bounds__(TPB)
void router_part(const float* __restrict__ x, const float* __restrict__ Wg,
                 float* __restrict__ part, int n_tokens, int ks) {
    __shared__ float xT[2][BK][XCOLS];   // 32 KB
    __shared__ float wT[2][BK][WCOLS];   // 16 KB

    const int tid   = threadIdx.x;
    const int nblkt = n_tokens / BM;            // 128
    const int tb    = blockIdx.x % nblkt;
    const int s     = blockIdx.x / nblkt;       // K-split index
    const int KC    = DIM / ks;
    const int k0    = s * KC;
    const int t0    = tb * BM;

    const int tt    = tid >> 3;                 // 0..15 token octet
    const int ee    = tid & 7;                  // 0..7  expert octet
    const int wrow  = tid & 63;                 // W row 0..63
    const int whalf = tid >> 6;                 // 0/1: 16-k half

    f32x2 acc[8][4];
#pragma unroll
    for (int i = 0; i < 8; ++i)
#pragma unroll
        for (int jp = 0; jp < 4; ++jp) acc[i][jp] = (f32x2)(0.f);

    const float* xrow = x + (size_t)(t0 + tid) * DIM + k0;
    const float* wrp  = Wg + (size_t)wrow * DIM + k0 + whalf * 16;

    f32x4 pxA[8], pwA[4], pxB[8], pwB[4];

#define LOADR(PX, PW, C) do {                                                  \
        const float* xp_ = xrow + (C) * BK;                                    \
        _Pragma("unroll")                                                      \
        for (int q = 0; q < 8; ++q) PX[q] = *(const f32x4*)(xp_ + q * 4);      \
        const float* wp_ = wrp + (C) * BK;                                     \
        _Pragma("unroll")                                                      \
        for (int q = 0; q < 4; ++q) PW[q] = *(const f32x4*)(wp_ + q * 4);      \
    } while (0)

#define STAGE(B, PX, PW) do {                                                  \
        _Pragma("unroll")                                                      \
        for (int q = 0; q < 8; ++q)                                            \
            _Pragma("unroll")                                                  \
            for (int j = 0; j < 4; ++j) {                                      \
                const int k_ = q * 4 + j;                                      \
                xT[B][k_][tid ^ SW(k_)] = PX[q][j];                            \
            }                                                                  \
        _Pragma("unroll")                                                      \
        for (int q = 0; q < 4; ++q)                                            \
            _Pragma("unroll")                                                  \
            for (int j = 0; j < 4; ++j) {                                      \
                const int k_ = whalf * 16 + q * 4 + j;                         \
                wT[B][k_][wrow ^ SW(k_)] = PW[q][j];                           \
            }                                                                  \
    } while (0)

#define COMPUTE(B) do {                                                        \
        _Pragma("unroll")                                                      \
        for (int kk = 0; kk < BK; ++kk) {                                      \
            const int sw_ = SW(kk);                                            \
            f32x4 xv0 = *(const f32x4*)&xT[B][kk][(tt * 8) ^ sw_];             \
            f32x4 xv1 = *(const f32x4*)&xT[B][kk][(tt * 8 + 4) ^ sw_];         \
            f32x4 w0  = *(const f32x4*)&wT[B][kk][(ee * 8) ^ sw_];             \
            f32x4 w1  = *(const f32x4*)&wT[B][kk][(ee * 8 + 4) ^ sw_];         \
            f32x2 wp0 = {w0.x, w0.y}, wp1 = {w0.z, w0.w};                      \
            f32x2 wp2 = {w1.x, w1.y}, wp3 = {w1.z, w1.w};                      \
            _Pragma("unroll")                                                  \
            for (int i = 0; i < 4; ++i) {                                      \
                f32x2 xa = {xv0[i], xv0[i]};                                   \
                acc[i][0] = __builtin_elementwise_fma(xa, wp0, acc[i][0]);     \
                acc[i][1] = __builtin_elementwise_fma(xa, wp1, acc[i][1]);     \
                acc[i][2] = __builtin_elementwise_fma(xa, wp2, acc[i][2]);     \
                acc[i][3] = __builtin_elementwise_fma(xa, wp3, acc[i][3]);     \
                f32x2 xb = {xv1[i], xv1[i]};                                   \
                acc[4+i][0] = __builtin_elementwise_fma(xb, wp0, acc[4+i][0]); \
                acc[4+i][1] = __builtin_elementwise_fma(xb, wp1, acc[4+i][1]); \
                acc[4+i][2] = __builtin_elementwise_fma(xb, wp2, acc[4+i][2]); \
                acc[4+i][3] = __builtin_elementwise_fma(xb, wp3, acc[4+i][3]); \
            }                                                                  \
        }                                                                      \
    } while (0)

    const int nch = KC / BK;   // 16 for ks=4 (always even)

    // prologue
    LOADR(pxA, pwA, 0);
    STAGE(0, pxA, pwA);
    LOADR(pxB, pwB, 1);
    __syncthreads();

    for (int c = 0; c < nch; c += 2) {
        // iter c: stage c+1 from B-regs, issue loads c+2 into A-regs, compute buf0
        STAGE(1, pxB, pwB);
        if (c + 2 < nch) LOADR(pxA, pwA, c + 2);
        COMPUTE(0);
        __syncthreads();
        // iter c+1: stage c+2 from A-regs, issue loads c+3 into B-regs, compute buf1
        if (c + 2 < nch) {
            STAGE(0, pxA, pwA);
            if (c + 3 < nch) LOADR(pxB, pwB, c + 3);
        }
        COMPUTE(1);
        __syncthreads();
    }

#undef LOADR
#undef STAGE
#undef COMPUTE

    // store partials: part[(tok*ks + s)*64 + e], 2 x f32x4 per token
#pragma unroll
    for (int i = 0; i < 8; ++i) {
        const int t = t0 + tt * 8 + i;
        float* pb = part + ((size_t)t * ks + s) * NEXP + ee * 8;
        f32x4 v0, v1;
        v0.x = acc[i][0].x; v0.y = acc[i][0].y; v0.z = acc[i][1].x; v0.w = acc[i][1].y;
        v1.x = acc[i][2].x; v1.y = acc[i][2].y; v1.z = acc[i][3].x; v1.w = acc[i][3].y;
        *(f32x4*)(pb)     = v0;
        *(f32x4*)(pb + 4) = v1;
    }
}

// ---------------- Kernel 2: reduce partials + softmax + top-2 + aux ----------
#define FTPB 64
__global__ __launch_bounds__(FTPB)
void router_finish(const float* __restrict__ part, float* __restrict__ out,
                   float* __restrict__ gCnt, float* __restrict__ gPsum,
                   int n_tokens, int ks) {
    __shared__ float pl[FTPB][NEXP + 1];
    __shared__ float cnt[NEXP];
    const int tid = threadIdx.x;
    const int tok = blockIdx.x * FTPB + tid;
    cnt[tid] = 0.f;                            // FTPB == NEXP
    __syncthreads();

    const float* pb = part + (size_t)tok * ks * NEXP;
    float lg[NEXP];
#pragma unroll
    for (int q = 0; q < 16; ++q) {
        f32x4 a = *(const f32x4*)(pb + q * 4);
        lg[q * 4 + 0] = a.x; lg[q * 4 + 1] = a.y;
        lg[q * 4 + 2] = a.z; lg[q * 4 + 3] = a.w;
    }
    for (int s2 = 1; s2 < ks; ++s2) {
#pragma unroll
        for (int q = 0; q < 16; ++q) {
            f32x4 a = *(const f32x4*)(pb + (size_t)s2 * NEXP + q * 4);
            lg[q * 4 + 0] += a.x; lg[q * 4 + 1] += a.y;
            lg[q * 4 + 2] += a.z; lg[q * 4 + 3] += a.w;
        }
    }

    // top-2 (strict > keeps lowest index on ties, matching lax.top_k)
    float m1 = -1e30f, m2 = -1e30f;
    int i1 = 0, i2 = 0;
#pragma unroll
    for (int e = 0; e < NEXP; ++e) {
        float l = lg[e];
        if (l > m1)      { m2 = m1; i2 = i1; m1 = l; i1 = e; }
        else if (l > m2) { m2 = l; i2 = e; }
    }

    float ssum = 0.f;
#pragma unroll
    for (int e = 0; e < NEXP; ++e) {
        float p = __expf(lg[e] - m1);
        lg[e] = p;
        ssum += p;
    }
    const float inv_s = 1.f / ssum;
#pragma unroll
    for (int e = 0; e < NEXP; ++e) pl[tid][e] = lg[e] * inv_s;

    const float p1 = inv_s;                    // exp(0)*inv_s
    const float p2 = __expf(m2 - m1) * inv_s;
    const float d  = p1 + p2 + 1e-8f;
    out[(size_t)tok * 2]     = (float)i1;
    out[(size_t)tok * 2 + 1] = (float)i2;
    out[(size_t)n_tokens * 2 + (size_t)tok * 2]     = p1 / d;
    out[(size_t)n_tokens * 2 + (size_t)tok * 2 + 1] = p2 / d;
    atomicAdd(&cnt[i1], 1.f);
    atomicAdd(&cnt[i2], 1.f);
    __syncthreads();

    // per-expert column sums of router_probs (thread e handles expert e)
    {
        float cs = 0.f;
#pragma unroll 8
        for (int t = 0; t < FTPB; ++t) cs += pl[t][tid];
        atomicAdd(&gPsum[tid], cs);
        atomicAdd(&gCnt[tid], cnt[tid]);
    }
}

// ---------------- Kernel 3: final aux loss -----------------------------------
__global__ void router_aux(const float* __restrict__ gCnt,
                           const float* __restrict__ gPsum,
                           float* __restrict__ out, int n_tokens) {
    const int e = threadIdx.x;
    float f = gCnt[e] / (float)(n_tokens * 2);
    float P = gPsum[e] / (float)n_tokens;
    float v = f * P;
#pragma unroll
    for (int o = 32; o > 0; o >>= 1) v += __shfl_down(v, o);
    if (e == 0) out[(size_t)n_tokens * 4] = 64.f * v;
}

extern "C" void kernel_launch(void* const* d_in, const int* in_sizes, int n_in,
                              void* d_out, int out_size, void* d_ws, size_t ws_size,
                              hipStream_t stream) {
    const float* x  = (const float*)d_in[0];
    const float* Wg = (const float*)d_in[1];
    float* out = (float*)d_out;
    const int n_tokens = in_sizes[0] / DIM;   // 16384

    // ks=4: grid 512 = exactly 2 blocks/CU (48KB LDS dbuf), partials 16.8MB
    int ks = 4;
    while (ks > 1 &&
           (2 * NEXP + (size_t)ks * n_tokens * NEXP) * sizeof(float) > ws_size)
        ks >>= 1;

    float* gCnt  = (float*)d_ws;
    float* gPsum = gCnt + NEXP;
    float* partb = gPsum + NEXP;

    hipMemsetAsync(d_ws, 0, 2 * NEXP * sizeof(float), stream);
    hipLaunchKernelGGL(router_part, dim3((n_tokens / BM) * ks), dim3(TPB), 0, stream,
                       x, Wg, partb, n_tokens, ks);
    hipLaunchKernelGGL(router_finish, dim3(n_tokens / FTPB), dim3(FTPB), 0, stream,
                       partb, out, gCnt, gPsum, n_tokens, ks);
    hipLaunchKernelGGL(router_aux, dim3(1), dim3(NEXP), 0, stream,
                       gCnt, gPsum, out, n_tokens);
}

// Round 9
// 100.720 us; speedup vs baseline: 2.6641x; 2.6641x over previous
//
#include <hip/hip_runtime.h>
#include <math.h>

#define DIM    2048
#define NEXP   64
#define BM     128
#define BK     16
#define TPB    128
#define XCOLS  128
#define WCOLS  64

typedef float f32x2 __attribute__((ext_vector_type(2)));
typedef float f32x4 __attribute__((ext_vector_type(4)));

// XOR swizzle (units of 4 floats). Writes: 64 lanes of a wave hit 64 distinct
// cols = 2 lanes/bank (free). Reads: 8-lane broadcast groups at stride-8 cols
// = 2-way max (free). Mult-of-4 => 16B alignment preserved under XOR.
#define SW(k) ((((k) >> 1) & 7) << 2)

// ---------------- Kernel 1: partial logits GEMM (packed fp32 FMA) ------------
// 128 tokens x 64 experts per block, 128 threads, per-thread 8 tok x 8 exp.
// Double-buffered LDS (24KB), ONE barrier per chunk. Per chunk: issue next
// loads -> compute current buf -> stage regs into other buf -> barrier.
// Loads are in flight across the whole compute phase; the vmcnt wait before
// the ds_writes (and the barrier's implicit drain) are therefore free.
__global__ __launch_bounds__(TPB)
void router_part(const float* __restrict__ x, const float* __restrict__ Wg,
                 float* __restrict__ part, int n_tokens, int ks) {
    __shared__ float xT[2][BK][XCOLS];   // 16 KB
    __shared__ float wT[2][BK][WCOLS];   //  8 KB

    const int tid   = threadIdx.x;
    const int nblkt = n_tokens / BM;            // 128
    const int tb    = blockIdx.x % nblkt;
    const int s     = blockIdx.x / nblkt;       // K-split index
    const int KC    = DIM / ks;
    const int k0    = s * KC;
    const int t0    = tb * BM;

    const int tt    = tid >> 3;                 // 0..15 token octet
    const int ee    = tid & 7;                  // 0..7  expert octet
    const int wrow  = tid & 63;                 // W row 0..63
    const int whalf = tid >> 6;                 // 0/1: 8-k half

    f32x2 acc[8][4];
#pragma unroll
    for (int i = 0; i < 8; ++i)
#pragma unroll
        for (int jp = 0; jp < 4; ++jp) acc[i][jp] = (f32x2)(0.f);

    const float* xrow = x + (size_t)(t0 + tid) * DIM + k0;
    const float* wrp  = Wg + (size_t)wrow * DIM + k0 + whalf * 8;

    f32x4 px[4], pw[2];

#define LOADR(C) do {                                                          \
        const float* xp_ = xrow + (C) * BK;                                    \
        _Pragma("unroll")                                                      \
        for (int q = 0; q < 4; ++q) px[q] = *(const f32x4*)(xp_ + q * 4);      \
        const float* wp_ = wrp + (C) * BK;                                     \
        _Pragma("unroll")                                                      \
        for (int q = 0; q < 2; ++q) pw[q] = *(const f32x4*)(wp_ + q * 4);      \
    } while (0)

#define STAGE(B) do {                                                          \
        _Pragma("unroll")                                                      \
        for (int q = 0; q < 4; ++q)                                            \
            _Pragma("unroll")                                                  \
            for (int j = 0; j < 4; ++j) {                                      \
                const int k_ = q * 4 + j;                                      \
                xT[B][k_][tid ^ SW(k_)] = px[q][j];                            \
            }                                                                  \
        _Pragma("unroll")                                                      \
        for (int q = 0; q < 2; ++q)                                            \
            _Pragma("unroll")                                                  \
            for (int j = 0; j < 4; ++j) {                                      \
                const int k_ = whalf * 8 + q * 4 + j;                          \
                wT[B][k_][wrow ^ SW(k_)] = pw[q][j];                           \
            }                                                                  \
    } while (0)

#define COMPUTE(B) do {                                                        \
        _Pragma("unroll")                                                      \
        for (int kk = 0; kk < BK; ++kk) {                                      \
            const int sw_ = SW(kk);                                            \
            f32x4 xv0 = *(const f32x4*)&xT[B][kk][(tt * 8) ^ sw_];             \
            f32x4 xv1 = *(const f32x4*)&xT[B][kk][(tt * 8 + 4) ^ sw_];         \
            f32x4 w0  = *(const f32x4*)&wT[B][kk][(ee * 8) ^ sw_];             \
            f32x4 w1  = *(const f32x4*)&wT[B][kk][(ee * 8 + 4) ^ sw_];         \
            f32x2 wp0 = {w0.x, w0.y}, wp1 = {w0.z, w0.w};                      \
            f32x2 wp2 = {w1.x, w1.y}, wp3 = {w1.z, w1.w};                      \
            _Pragma("unroll")                                                  \
            for (int i = 0; i < 4; ++i) {                                      \
                f32x2 xa = {xv0[i], xv0[i]};                                   \
                acc[i][0] = __builtin_elementwise_fma(xa, wp0, acc[i][0]);     \
                acc[i][1] = __builtin_elementwise_fma(xa, wp1, acc[i][1]);     \
                acc[i][2] = __builtin_elementwise_fma(xa, wp2, acc[i][2]);     \
                acc[i][3] = __builtin_elementwise_fma(xa, wp3, acc[i][3]);     \
                f32x2 xb = {xv1[i], xv1[i]};                                   \
                acc[4+i][0] = __builtin_elementwise_fma(xb, wp0, acc[4+i][0]); \
                acc[4+i][1] = __builtin_elementwise_fma(xb, wp1, acc[4+i][1]); \
                acc[4+i][2] = __builtin_elementwise_fma(xb, wp2, acc[4+i][2]); \
                acc[4+i][3] = __builtin_elementwise_fma(xb, wp3, acc[4+i][3]); \
            }                                                                  \
        }                                                                      \
    } while (0)

    const int nch = KC / BK;   // 16 for ks=8

    // prologue: chunk 0 into buf0 (its barrier drain is the only exposed load)
    LOADR(0);
    STAGE(0);
    __syncthreads();

    for (int c = 0; c < nch; ++c) {
        const int cur = c & 1;
        if (c + 1 < nch) LOADR(c + 1);        // issue loads (in flight)
        COMPUTE(cur);                          // ~long compute hides them
        if (c + 1 < nch) STAGE(cur ^ 1);       // vmcnt wait is free here
        __syncthreads();
    }

#undef LOADR
#undef STAGE
#undef COMPUTE

    // store partials: part[(tok*ks + s)*64 + e], 2 x f32x4 per token
#pragma unroll
    for (int i = 0; i < 8; ++i) {
        const int t = t0 + tt * 8 + i;
        float* pb = part + ((size_t)t * ks + s) * NEXP + ee * 8;
        f32x4 v0, v1;
        v0.x = acc[i][0].x; v0.y = acc[i][0].y; v0.z = acc[i][1].x; v0.w = acc[i][1].y;
        v1.x = acc[i][2].x; v1.y = acc[i][2].y; v1.z = acc[i][3].x; v1.w = acc[i][3].y;
        *(f32x4*)(pb)     = v0;
        *(f32x4*)(pb + 4) = v1;
    }
}

// ---------------- Kernel 2: reduce partials + softmax + top-2 + aux ----------
#define FTPB 64
__global__ __launch_bounds__(FTPB)
void router_finish(const float* __restrict__ part, float* __restrict__ out,
                   float* __restrict__ gCnt, float* __restrict__ gPsum,
                   int n_tokens, int ks) {
    __shared__ float pl[FTPB][NEXP + 1];
    __shared__ float cnt[NEXP];
    const int tid = threadIdx.x;
    const int tok = blockIdx.x * FTPB + tid;
    cnt[tid] = 0.f;                            // FTPB == NEXP
    __syncthreads();

    const float* pb = part + (size_t)tok * ks * NEXP;
    float lg[NEXP];
#pragma unroll
    for (int q = 0; q < 16; ++q) {
        f32x4 a = *(const f32x4*)(pb + q * 4);
        lg[q * 4 + 0] = a.x; lg[q * 4 + 1] = a.y;
        lg[q * 4 + 2] = a.z; lg[q * 4 + 3] = a.w;
    }
    for (int s2 = 1; s2 < ks; ++s2) {
#pragma unroll
        for (int q = 0; q < 16; ++q) {
            f32x4 a = *(const f32x4*)(pb + (size_t)s2 * NEXP + q * 4);
            lg[q * 4 + 0] += a.x; lg[q * 4 + 1] += a.y;
            lg[q * 4 + 2] += a.z; lg[q * 4 + 3] += a.w;
        }
    }

    // top-2 (strict > keeps lowest index on ties, matching lax.top_k)
    float m1 = -1e30f, m2 = -1e30f;
    int i1 = 0, i2 = 0;
#pragma unroll
    for (int e = 0; e < NEXP; ++e) {
        float l = lg[e];
        if (l > m1)      { m2 = m1; i2 = i1; m1 = l; i1 = e; }
        else if (l > m2) { m2 = l; i2 = e; }
    }

    float ssum = 0.f;
#pragma unroll
    for (int e = 0; e < NEXP; ++e) {
        float p = __expf(lg[e] - m1);
        lg[e] = p;
        ssum += p;
    }
    const float inv_s = 1.f / ssum;
#pragma unroll
    for (int e = 0; e < NEXP; ++e) pl[tid][e] = lg[e] * inv_s;

    const float p1 = inv_s;                    // exp(0)*inv_s
    const float p2 = __expf(m2 - m1) * inv_s;
    const float d  = p1 + p2 + 1e-8f;
    out[(size_t)tok * 2]     = (float)i1;
    out[(size_t)tok * 2 + 1] = (float)i2;
    out[(size_t)n_tokens * 2 + (size_t)tok * 2]     = p1 / d;
    out[(size_t)n_tokens * 2 + (size_t)tok * 2 + 1] = p2 / d;
    atomicAdd(&cnt[i1], 1.f);
    atomicAdd(&cnt[i2], 1.f);
    __syncthreads();

    // per-expert column sums of router_probs (thread e handles expert e)
    {
        float cs = 0.f;
#pragma unroll 8
        for (int t = 0; t < FTPB; ++t) cs += pl[t][tid];
        atomicAdd(&gPsum[tid], cs);
        atomicAdd(&gCnt[tid], cnt[tid]);
    }
}

// ---------------- Kernel 3: final aux loss -----------------------------------
__global__ void router_aux(const float* __restrict__ gCnt,
                           const float* __restrict__ gPsum,
                           float* __restrict__ out, int n_tokens) {
    const int e = threadIdx.x;
    float f = gCnt[e] / (float)(n_tokens * 2);
    float P = gPsum[e] / (float)n_tokens;
    float v = f * P;
#pragma unroll
    for (int o = 32; o > 0; o >>= 1) v += __shfl_down(v, o);
    if (e == 0) out[(size_t)n_tokens * 4] = 64.f * v;
}

extern "C" void kernel_launch(void* const* d_in, const int* in_sizes, int n_in,
                              void* d_out, int out_size, void* d_ws, size_t ws_size,
                              hipStream_t stream) {
    const float* x  = (const float*)d_in[0];
    const float* Wg = (const float*)d_in[1];
    float* out = (float*)d_out;
    const int n_tokens = in_sizes[0] / DIM;   // 16384

    // ks=8: grid 1024 = 4 blocks/CU resident (24KB LDS, ~110 VGPR), 2 waves/SIMD
    int ks = 8;
    while (ks > 1 &&
           (2 * NEXP + (size_t)ks * n_tokens * NEXP) * sizeof(float) > ws_size)
        ks >>= 1;

    float* gCnt  = (float*)d_ws;
    float* gPsum = gCnt + NEXP;
    float* partb = gPsum + NEXP;

    hipMemsetAsync(d_ws, 0, 2 * NEXP * sizeof(float), stream);
    hipLaunchKernelGGL(router_part, dim3((n_tokens / BM) * ks), dim3(TPB), 0, stream,
                       x, Wg, partb, n_tokens, ks);
    hipLaunchKernelGGL(router_finish, dim3(n_tokens / FTPB), dim3(FTPB), 0, stream,
                       partb, out, gCnt, gPsum, n_tokens, ks);
    hipLaunchKernelGGL(router_aux, dim3(1), dim3(NEXP), 0, stream,
                       gCnt, gPsum, out, n_tokens);
}

// Round 10
// 75.190 us; speedup vs baseline: 3.5687x; 1.3395x over previous
//
#include <hip/hip_runtime.h>
#include <math.h>

#define DIM   2048
#define NEXP  64
#define BM    64
#define TPB   512
#define BK    64
#define NCH   (DIM / BK)   // 32

typedef float f32x4  __attribute__((ext_vector_type(4)));
typedef short bf16x8 __attribute__((ext_vector_type(8)));
typedef unsigned short u16;

// ---- fp32 -> 3-term bf16 split (RNE). Error ~2^-26 relative: index-safe. ----
__device__ __forceinline__ u16 rne_bf16(float f) {
    union { float f; unsigned u; } v; v.f = f;
    unsigned u = v.u;
    u += 0x7fffu + ((u >> 16) & 1u);
    return (u16)(u >> 16);
}
__device__ __forceinline__ float bf2f(u16 h) {
    union { unsigned u; float f; } v; v.u = ((unsigned)h) << 16;
    return v.f;
}
__device__ __forceinline__ void split3(float x, u16& a, u16& b, u16& c) {
    a = rne_bf16(x);
    float r1 = x - bf2f(a);
    b = rne_bf16(r1);
    float r2 = r1 - bf2f(b);
    c = rne_bf16(r2);
}

// ---------------- Kernel 0: W -> 3 bf16 planes, MFMA-B-fragment-linear -------
// Layout (u16): wp[(kstep*4 + etile)*3 + plane][lane][8]
// fragment element: W[16*etile + (lane&15)][32*kstep + 8*(lane>>4) + i]
__global__ __launch_bounds__(256)
void wconv(const float* __restrict__ Wg, u16* __restrict__ wp) {
    const int G  = blockIdx.x * 256 + threadIdx.x;   // 0..16383
    const int l  = G & 63;
    const int r  = G >> 6;                           // kstep*4 + etile, 0..255
    const int ks = r >> 2, et = r & 3;
    const int ex = et * 16 + (l & 15);
    const int k  = ks * 32 + (l >> 4) * 8;
    const float* src = Wg + (size_t)ex * DIM + k;
    f32x4 v0 = *(const f32x4*)src;
    f32x4 v1 = *(const f32x4*)(src + 4);
    u16 h0[8], h1[8], h2[8];
#pragma unroll
    for (int i = 0; i < 8; ++i) {
        float xv = (i < 4) ? v0[i] : v1[i - 4];
        split3(xv, h0[i], h1[i], h2[i]);
    }
    u16* dst = wp + ((size_t)r * 3) * 512 + l * 8;
    *(bf16x8*)(dst)        = *(bf16x8*)h0;
    *(bf16x8*)(dst + 512)  = *(bf16x8*)h1;
    *(bf16x8*)(dst + 1024) = *(bf16x8*)h2;
}

// ---------------- Kernel 1: fused MFMA logits + softmax + top-2 + aux --------
// Block: 64 tokens x 64 experts, 512 threads = 8 waves (4 tok-tiles x 2 e-halves).
// x staged fragment-linear in LDS (lane-strided 16B: conflict-free by constr.);
// W fragments read straight from L2 (global), never via LDS.
__global__ __launch_bounds__(TPB)
void router_main(const float* __restrict__ x, const u16* __restrict__ wp,
                 float* __restrict__ out, float* __restrict__ gCnt,
                 float* __restrict__ gPsum, int n_tokens) {
    __shared__ __align__(16) u16 xp[2][2][4][3][64][8]; // [buf][s][tt][p][lane][8] 24KB
    __shared__ float ls[BM][NEXP + 1];
    __shared__ float cnt[NEXP];
    __shared__ float rs[BM];

    const int tid  = threadIdx.x;
    const int t0   = blockIdx.x * BM;
    const int lane = tid & 63;
    const int wid  = tid >> 6;       // 0..7
    const int g_s  = wid & 1;        // staging: kstep half
    const int g_tt = wid >> 1;       // staging: tok-tile 0..3
    const int wr   = wid >> 1;       // compute: tok-tile 0..3
    const int wc   = wid & 1;        // compute: expert half 0..1

    if (tid < NEXP) cnt[tid] = 0.f;

    f32x4 acc0 = {0.f, 0.f, 0.f, 0.f};   // e-tile 2*wc
    f32x4 acc1 = {0.f, 0.f, 0.f, 0.f};   // e-tile 2*wc+1

    const float* xsrc = x + (size_t)(t0 + 16 * g_tt + (lane & 15)) * DIM + 8 * (lane >> 4);
    f32x4 px0, px1;

#define LOADX(C) do {                                                          \
        const float* p_ = xsrc + (C) * BK + 32 * g_s;                          \
        px0 = *(const f32x4*)p_;                                               \
        px1 = *(const f32x4*)(p_ + 4);                                         \
    } while (0)

#define STAGEX(B) do {                                                         \
        u16 a_[8], b_[8], c_[8];                                               \
        _Pragma("unroll")                                                      \
        for (int i = 0; i < 8; ++i) {                                          \
            float xv = (i < 4) ? px0[i] : px1[i - 4];                          \
            split3(xv, a_[i], b_[i], c_[i]);                                   \
        }                                                                      \
        *(bf16x8*)&xp[B][g_s][g_tt][0][lane][0] = *(bf16x8*)a_;                \
        *(bf16x8*)&xp[B][g_s][g_tt][1][lane][0] = *(bf16x8*)b_;                \
        *(bf16x8*)&xp[B][g_s][g_tt][2][lane][0] = *(bf16x8*)c_;                \
    } while (0)

    // prologue
    LOADX(0);
    STAGEX(0);
    __syncthreads();

    for (int c = 0; c < NCH; ++c) {
        const int cur = c & 1;
        // B fragments for this chunk (2 ksteps x 2 e-tiles x 3 planes), L2-hot.
        bf16x8 Bf[2][2][3];
#pragma unroll
        for (int s = 0; s < 2; ++s)
#pragma unroll
            for (int et = 0; et < 2; ++et) {
                const size_t r_ = (size_t)((c * 2 + s) * 4 + 2 * wc + et) * 3;
#pragma unroll
                for (int p = 0; p < 3; ++p)
                    Bf[s][et][p] = *(const bf16x8*)(wp + (r_ + p) * 512 + lane * 8);
            }
        // issue next x loads AFTER B (vmcnt waits for B won't drain them)
        if (c + 1 < NCH) LOADX(c + 1);
        // MFMA: 6-product 3-term split per (s, e-tile)
#pragma unroll
        for (int s = 0; s < 2; ++s) {
            bf16x8 A0 = *(const bf16x8*)&xp[cur][s][wr][0][lane][0];
            bf16x8 A1 = *(const bf16x8*)&xp[cur][s][wr][1][lane][0];
            bf16x8 A2 = *(const bf16x8*)&xp[cur][s][wr][2][lane][0];
            acc0 = __builtin_amdgcn_mfma_f32_16x16x32_bf16(A0, Bf[s][0][0], acc0, 0, 0, 0);
            acc0 = __builtin_amdgcn_mfma_f32_16x16x32_bf16(A0, Bf[s][0][1], acc0, 0, 0, 0);
            acc0 = __builtin_amdgcn_mfma_f32_16x16x32_bf16(A1, Bf[s][0][0], acc0, 0, 0, 0);
            acc0 = __builtin_amdgcn_mfma_f32_16x16x32_bf16(A1, Bf[s][0][1], acc0, 0, 0, 0);
            acc0 = __builtin_amdgcn_mfma_f32_16x16x32_bf16(A0, Bf[s][0][2], acc0, 0, 0, 0);
            acc0 = __builtin_amdgcn_mfma_f32_16x16x32_bf16(A2, Bf[s][0][0], acc0, 0, 0, 0);
            acc1 = __builtin_amdgcn_mfma_f32_16x16x32_bf16(A0, Bf[s][1][0], acc1, 0, 0, 0);
            acc1 = __builtin_amdgcn_mfma_f32_16x16x32_bf16(A0, Bf[s][1][1], acc1, 0, 0, 0);
            acc1 = __builtin_amdgcn_mfma_f32_16x16x32_bf16(A1, Bf[s][1][0], acc1, 0, 0, 0);
            acc1 = __builtin_amdgcn_mfma_f32_16x16x32_bf16(A1, Bf[s][1][1], acc1, 0, 0, 0);
            acc1 = __builtin_amdgcn_mfma_f32_16x16x32_bf16(A0, Bf[s][1][2], acc1, 0, 0, 0);
            acc1 = __builtin_amdgcn_mfma_f32_16x16x32_bf16(A2, Bf[s][1][0], acc1, 0, 0, 0);
        }
        // stage next chunk (vmcnt wait on px here, hidden under the MFMAs)
        if (c + 1 < NCH) STAGEX(cur ^ 1);
        __syncthreads();
    }
#undef LOADX
#undef STAGEX

    // ---- epilogue: logits -> LDS (C-layout: col=lane&15, row=4*(lane>>4)+reg)
    {
        const int m0 = 16 * wr + 4 * (lane >> 4);
        const int n0 = 32 * wc + (lane & 15);
#pragma unroll
        for (int r2 = 0; r2 < 4; ++r2) {
            ls[m0 + r2][n0]      = acc0[r2];
            ls[m0 + r2][n0 + 16] = acc1[r2];
        }
    }
    __syncthreads();

    // ---- per-token top-2 + softmax: 8 threads per token ----
    const int tok = tid >> 3;        // 0..63
    const int sub = tid & 7;
    float l8[8];
#pragma unroll
    for (int j = 0; j < 8; ++j) l8[j] = ls[tok][sub * 8 + j];
    float m1 = -1e30f, m2 = -1e30f;
    int   i1 = 0, i2 = 0;
#pragma unroll
    for (int j = 0; j < 8; ++j) {
        float v = l8[j]; int e = sub * 8 + j;
        if (v > m1)      { m2 = m1; i2 = i1; m1 = v; i1 = e; }
        else if (v > m2) { m2 = v; i2 = e; }
    }
#pragma unroll
    for (int off = 1; off < 8; off <<= 1) {
        float n1 = __shfl_xor(m1, off, 8); int j1 = __shfl_xor(i1, off, 8);
        float n2 = __shfl_xor(m2, off, 8); int j2 = __shfl_xor(i2, off, 8);
        bool fb = (m1 > n1) || (m1 == n1 && i1 < j1);   // ties: lower index
        float a1 = fb ? m1 : n1;  int ai = fb ? i1 : j1;
        float b1 = fb ? n1 : m1;  int bi = fb ? j1 : i1;
        float c2 = fb ? m2 : n2;  int ci = fb ? i2 : j2;
        bool bb = (b1 > c2) || (b1 == c2 && bi < ci);
        m1 = a1; i1 = ai;
        m2 = bb ? b1 : c2; i2 = bb ? bi : ci;
    }
    float psum = 0.f;
#pragma unroll
    for (int j = 0; j < 8; ++j) {
        float p = __expf(l8[j] - m1);
        psum += p;
        ls[tok][sub * 8 + j] = p;    // unnormalized probs for column sums
    }
#pragma unroll
    for (int off = 1; off < 8; off <<= 1) psum += __shfl_xor(psum, off, 8);
    const float inv = 1.f / psum;
    if (sub == 0) {
        rs[tok] = inv;
        const float p1 = inv;                     // exp(0)*inv
        const float p2 = __expf(m2 - m1) * inv;
        const float d  = p1 + p2 + 1e-8f;
        const int tg = t0 + tok;
        out[(size_t)tg * 2]     = (float)i1;
        out[(size_t)tg * 2 + 1] = (float)i2;
        out[(size_t)n_tokens * 2 + (size_t)tg * 2]     = p1 / d;
        out[(size_t)n_tokens * 2 + (size_t)tg * 2 + 1] = p2 / d;
        atomicAdd(&cnt[i1], 1.f);
        atomicAdd(&cnt[i2], 1.f);
    }
    __syncthreads();

    // ---- per-expert column sums + global accumulation ----
    if (tid < NEXP) {
        float cs = 0.f;
#pragma unroll 8
        for (int t = 0; t < BM; ++t) cs += ls[t][tid] * rs[t];
        atomicAdd(&gPsum[tid], cs);
        atomicAdd(&gCnt[tid], cnt[tid]);
    }
}

// ---------------- Kernel 2: final aux loss -----------------------------------
__global__ void router_aux(const float* __restrict__ gCnt,
                           const float* __restrict__ gPsum,
                           float* __restrict__ out, int n_tokens) {
    const int e = threadIdx.x;
    float f = gCnt[e] / (float)(n_tokens * 2);
    float P = gPsum[e] / (float)n_tokens;
    float v = f * P;
#pragma unroll
    for (int o = 32; o > 0; o >>= 1) v += __shfl_down(v, o);
    if (e == 0) out[(size_t)n_tokens * 4] = 64.f * v;
}

extern "C" void kernel_launch(void* const* d_in, const int* in_sizes, int n_in,
                              void* d_out, int out_size, void* d_ws, size_t ws_size,
                              hipStream_t stream) {
    const float* x  = (const float*)d_in[0];
    const float* Wg = (const float*)d_in[1];
    float* out = (float*)d_out;
    const int n_tokens = in_sizes[0] / DIM;   // 16384

    // ws layout: wplanes (256*3*512 u16 = 786 KB), then gCnt/gPsum
    u16*   wplanes = (u16*)d_ws;
    float* gCnt    = (float*)((char*)d_ws + 256 * 3 * 512 * sizeof(u16));
    float* gPsum   = gCnt + NEXP;

    hipMemsetAsync(gCnt, 0, 2 * NEXP * sizeof(float), stream);
    hipLaunchKernelGGL(wconv, dim3(64), dim3(256), 0, stream, Wg, wplanes);
    hipLaunchKernelGGL(router_main, dim3(n_tokens / BM), dim3(TPB), 0, stream,
                       x, wplanes, out, gCnt, gPsum, n_tokens);
    hipLaunchKernelGGL(router_aux, dim3(1), dim3(NEXP), 0, stream,
                       gCnt, gPsum, out, n_tokens);
}

// Round 11
// 72.001 us; speedup vs baseline: 3.7268x; 1.0443x over previous
//
#include <hip/hip_runtime.h>
#include <math.h>

#define DIM   2048
#define NEXP  64
#define BM    64
#define TPB   512
#define BK    64
#define NCH   (DIM / BK)   // 32

typedef float f32x4  __attribute__((ext_vector_type(4)));
typedef short bf16x8 __attribute__((ext_vector_type(8)));
typedef unsigned short u16;

// ---- fp32 -> 3-term bf16 split (RNE). Error ~2^-26 relative: index-safe. ----
__device__ __forceinline__ u16 rne_bf16(float f) {
    union { float f; unsigned u; } v; v.f = f;
    unsigned u = v.u;
    u += 0x7fffu + ((u >> 16) & 1u);
    return (u16)(u >> 16);
}
__device__ __forceinline__ float bf2f(u16 h) {
    union { unsigned u; float f; } v; v.u = ((unsigned)h) << 16;
    return v.f;
}
__device__ __forceinline__ void split3(float x, u16& a, u16& b, u16& c) {
    a = rne_bf16(x);
    float r1 = x - bf2f(a);
    b = rne_bf16(r1);
    float r2 = r1 - bf2f(b);
    c = rne_bf16(r2);
}

// ---------------- Kernel 0: W -> 3 bf16 planes, MFMA-B-fragment-linear -------
// Layout (u16): wp[(kstep*4 + etile)*3 + plane][lane][8]
// fragment element: W[16*etile + (lane&15)][32*kstep + 8*(lane>>4) + i]
__global__ __launch_bounds__(256)
void wconv(const float* __restrict__ Wg, u16* __restrict__ wp) {
    const int G  = blockIdx.x * 256 + threadIdx.x;   // 0..16383
    const int l  = G & 63;
    const int r  = G >> 6;                           // kstep*4 + etile, 0..255
    const int ks = r >> 2, et = r & 3;
    const int ex = et * 16 + (l & 15);
    const int k  = ks * 32 + (l >> 4) * 8;
    const float* src = Wg + (size_t)ex * DIM + k;
    f32x4 v0 = *(const f32x4*)src;
    f32x4 v1 = *(const f32x4*)(src + 4);
    u16 h0[8], h1[8], h2[8];
#pragma unroll
    for (int i = 0; i < 8; ++i) {
        float xv = (i < 4) ? v0[i] : v1[i - 4];
        split3(xv, h0[i], h1[i], h2[i]);
    }
    u16* dst = wp + ((size_t)r * 3) * 512 + l * 8;
    *(bf16x8*)(dst)        = *(bf16x8*)h0;
    *(bf16x8*)(dst + 512)  = *(bf16x8*)h1;
    *(bf16x8*)(dst + 1024) = *(bf16x8*)h2;
}

// ---------------- Kernel 1: fused MFMA logits + softmax + top-2 + aux --------
// 64 tokens x 64 experts per block, 8 waves (4 tok-tiles x 2 e-halves).
// NO LDS and NO barriers in the main loop: each wave streams its own 16 token
// rows from global in A-fragment shape, split3s in registers, and MFMAs
// against L2-resident W fragments. Compiler free to pipeline across chunks.
__global__ __launch_bounds__(TPB, 2)
void router_main(const float* __restrict__ x, const u16* __restrict__ wp,
                 float* __restrict__ out, float* __restrict__ gCnt,
                 float* __restrict__ gPsum, int n_tokens) {
    __shared__ float ls[BM][NEXP + 1];
    __shared__ float cnt[NEXP];
    __shared__ float rs[BM];

    const int tid  = threadIdx.x;
    const int t0   = blockIdx.x * BM;
    const int lane = tid & 63;
    const int wid  = tid >> 6;       // 0..7
    const int wr   = wid >> 1;       // tok-tile 0..3
    const int wc   = wid & 1;        // expert half 0..1

    if (tid < NEXP) cnt[tid] = 0.f;

    f32x4 acc0 = {0.f, 0.f, 0.f, 0.f};   // e-tile 2*wc
    f32x4 acc1 = {0.f, 0.f, 0.f, 0.f};   // e-tile 2*wc+1

    // per-lane x source: row = own token (m = lane&15), k-offset 8*(lane>>4)
    const float* xsrc = x + (size_t)(t0 + 16 * wr + (lane & 15)) * DIM + 8 * (lane >> 4);
    // W fragment base for this e-half (et offset 2*wc), per-lane 16B
    const u16* wb = wp + ((size_t)2 * wc * 3) * 512 + lane * 8;

#pragma unroll 2
    for (int c = 0; c < NCH; ++c) {
        // ---- x: 2 ksteps x 8 floats per lane, straight from global ----
        const float* xp_ = xsrc + c * BK;
        f32x4 xr0 = *(const f32x4*)(xp_);
        f32x4 xr1 = *(const f32x4*)(xp_ + 4);
        f32x4 xr2 = *(const f32x4*)(xp_ + 32);
        f32x4 xr3 = *(const f32x4*)(xp_ + 36);
        // ---- B fragments: 2 ksteps x 2 e-tiles x 3 planes (L2-hot) ----
        bf16x8 Bf[2][2][3];
#pragma unroll
        for (int s = 0; s < 2; ++s)
#pragma unroll
            for (int et = 0; et < 2; ++et) {
                const u16* p_ = wb + ((size_t)((c * 2 + s) * 4 + et) * 3) * 512;
#pragma unroll
                for (int p = 0; p < 3; ++p)
                    Bf[s][et][p] = *(const bf16x8*)(p_ + (size_t)p * 512);
            }
        // ---- split3 x -> A fragments (registers only) ----
        bf16x8 A[2][3];
#pragma unroll
        for (int s = 0; s < 2; ++s) {
            u16 a_[8], b_[8], c_[8];
#pragma unroll
            for (int i = 0; i < 8; ++i) {
                float f = (s == 0) ? ((i < 4) ? xr0[i] : xr1[i - 4])
                                   : ((i < 4) ? xr2[i] : xr3[i - 4]);
                split3(f, a_[i], b_[i], c_[i]);
            }
            A[s][0] = *(bf16x8*)a_;
            A[s][1] = *(bf16x8*)b_;
            A[s][2] = *(bf16x8*)c_;
        }
        // ---- 24 MFMAs: 6-product 3-term split per (s, e-tile) ----
#pragma unroll
        for (int s = 0; s < 2; ++s) {
            acc0 = __builtin_amdgcn_mfma_f32_16x16x32_bf16(A[s][0], Bf[s][0][0], acc0, 0, 0, 0);
            acc0 = __builtin_amdgcn_mfma_f32_16x16x32_bf16(A[s][0], Bf[s][0][1], acc0, 0, 0, 0);
            acc0 = __builtin_amdgcn_mfma_f32_16x16x32_bf16(A[s][1], Bf[s][0][0], acc0, 0, 0, 0);
            acc0 = __builtin_amdgcn_mfma_f32_16x16x32_bf16(A[s][1], Bf[s][0][1], acc0, 0, 0, 0);
            acc0 = __builtin_amdgcn_mfma_f32_16x16x32_bf16(A[s][0], Bf[s][0][2], acc0, 0, 0, 0);
            acc0 = __builtin_amdgcn_mfma_f32_16x16x32_bf16(A[s][2], Bf[s][0][0], acc0, 0, 0, 0);
            acc1 = __builtin_amdgcn_mfma_f32_16x16x32_bf16(A[s][0], Bf[s][1][0], acc1, 0, 0, 0);
            acc1 = __builtin_amdgcn_mfma_f32_16x16x32_bf16(A[s][0], Bf[s][1][1], acc1, 0, 0, 0);
            acc1 = __builtin_amdgcn_mfma_f32_16x16x32_bf16(A[s][1], Bf[s][1][0], acc1, 0, 0, 0);
            acc1 = __builtin_amdgcn_mfma_f32_16x16x32_bf16(A[s][1], Bf[s][1][1], acc1, 0, 0, 0);
            acc1 = __builtin_amdgcn_mfma_f32_16x16x32_bf16(A[s][0], Bf[s][1][2], acc1, 0, 0, 0);
            acc1 = __builtin_amdgcn_mfma_f32_16x16x32_bf16(A[s][2], Bf[s][1][0], acc1, 0, 0, 0);
        }
    }

    // ---- epilogue: logits -> LDS (C-layout: col=lane&15, row=4*(lane>>4)+reg)
    {
        const int m0 = 16 * wr + 4 * (lane >> 4);
        const int n0 = 32 * wc + (lane & 15);
#pragma unroll
        for (int r2 = 0; r2 < 4; ++r2) {
            ls[m0 + r2][n0]      = acc0[r2];
            ls[m0 + r2][n0 + 16] = acc1[r2];
        }
    }
    __syncthreads();

    // ---- per-token top-2 + softmax: 8 threads per token ----
    const int tok = tid >> 3;        // 0..63
    const int sub = tid & 7;
    float l8[8];
#pragma unroll
    for (int j = 0; j < 8; ++j) l8[j] = ls[tok][sub * 8 + j];
    float m1 = -1e30f, m2 = -1e30f;
    int   i1 = 0, i2 = 0;
#pragma unroll
    for (int j = 0; j < 8; ++j) {
        float v = l8[j]; int e = sub * 8 + j;
        if (v > m1)      { m2 = m1; i2 = i1; m1 = v; i1 = e; }
        else if (v > m2) { m2 = v; i2 = e; }
    }
#pragma unroll
    for (int off = 1; off < 8; off <<= 1) {
        float n1 = __shfl_xor(m1, off, 8); int j1 = __shfl_xor(i1, off, 8);
        float n2 = __shfl_xor(m2, off, 8); int j2 = __shfl_xor(i2, off, 8);
        bool fb = (m1 > n1) || (m1 == n1 && i1 < j1);   // ties: lower index
        float a1 = fb ? m1 : n1;  int ai = fb ? i1 : j1;
        float b1 = fb ? n1 : m1;  int bi = fb ? j1 : i1;
        float c2 = fb ? m2 : n2;  int ci = fb ? i2 : j2;
        bool bb = (b1 > c2) || (b1 == c2 && bi < ci);
        m1 = a1; i1 = ai;
        m2 = bb ? b1 : c2; i2 = bb ? bi : ci;
    }
    float psum = 0.f;
#pragma unroll
    for (int j = 0; j < 8; ++j) {
        float p = __expf(l8[j] - m1);
        psum += p;
        ls[tok][sub * 8 + j] = p;    // unnormalized probs for column sums
    }
#pragma unroll
    for (int off = 1; off < 8; off <<= 1) psum += __shfl_xor(psum, off, 8);
    const float inv = 1.f / psum;
    if (sub == 0) {
        rs[tok] = inv;
        const float p1 = inv;                     // exp(0)*inv
        const float p2 = __expf(m2 - m1) * inv;
        const float d  = p1 + p2 + 1e-8f;
        const int tg = t0 + tok;
        out[(size_t)tg * 2]     = (float)i1;
        out[(size_t)tg * 2 + 1] = (float)i2;
        out[(size_t)n_tokens * 2 + (size_t)tg * 2]     = p1 / d;
        out[(size_t)n_tokens * 2 + (size_t)tg * 2 + 1] = p2 / d;
        atomicAdd(&cnt[i1], 1.f);
        atomicAdd(&cnt[i2], 1.f);
    }
    __syncthreads();

    // ---- per-expert column sums + global accumulation ----
    if (tid < NEXP) {
        float cs = 0.f;
#pragma unroll 8
        for (int t = 0; t < BM; ++t) cs += ls[t][tid] * rs[t];
        atomicAdd(&gPsum[tid], cs);
        atomicAdd(&gCnt[tid], cnt[tid]);
    }
}

// ---------------- Kernel 2: final aux loss -----------------------------------
__global__ void router_aux(const float* __restrict__ gCnt,
                           const float* __restrict__ gPsum,
                           float* __restrict__ out, int n_tokens) {
    const int e = threadIdx.x;
    float f = gCnt[e] / (float)(n_tokens * 2);
    float P = gPsum[e] / (float)n_tokens;
    float v = f * P;
#pragma unroll
    for (int o = 32; o > 0; o >>= 1) v += __shfl_down(v, o);
    if (e == 0) out[(size_t)n_tokens * 4] = 64.f * v;
}

extern "C" void kernel_launch(void* const* d_in, const int* in_sizes, int n_in,
                              void* d_out, int out_size, void* d_ws, size_t ws_size,
                              hipStream_t stream) {
    const float* x  = (const float*)d_in[0];
    const float* Wg = (const float*)d_in[1];
    float* out = (float*)d_out;
    const int n_tokens = in_sizes[0] / DIM;   // 16384

    // ws layout: wplanes (256*3*512 u16 = 786 KB), then gCnt/gPsum
    u16*   wplanes = (u16*)d_ws;
    float* gCnt    = (float*)((char*)d_ws + 256 * 3 * 512 * sizeof(u16));
    float* gPsum   = gCnt + NEXP;

    hipMemsetAsync(gCnt, 0, 2 * NEXP * sizeof(float), stream);
    hipLaunchKernelGGL(wconv, dim3(64), dim3(256), 0, stream, Wg, wplanes);
    hipLaunchKernelGGL(router_main, dim3(n_tokens / BM), dim3(TPB), 0, stream,
                       x, wplanes, out, gCnt, gPsum, n_tokens);
    hipLaunchKernelGGL(router_aux, dim3(1), dim3(NEXP), 0, stream,
                       gCnt, gPsum, out, n_tokens);
}